// Round 5
// baseline (792.908 us; speedup 1.0000x reference)
//
#include <hip/hip_runtime.h>
#include <math.h>

#define B_    8
#define N_    2048
#define C_    512
#define CIN_  128
#define H_    96
#define W_    96
#define HW_   (H_*W_)          // 9216
#define IMG_  (CIN_*HW_)       // 1179648 elems per (batch, image)

// d_out float offsets (return order: y, lr0, lr1, lr2)
#define OUT_L0 (B_*N_*C_)               // 8388608
#define OUT_L1 (OUT_L0 + B_*N_*8)       // 8519680
#define OUT_L2 (OUT_L1 + B_*N_*16)      // 8781824

// numpy-exact f32 helpers (block FMA contraction / reassociation)
__device__ __forceinline__ float fm(float a, float b) { return __fmul_rn(a, b); }
__device__ __forceinline__ float fa(float a, float b) { return __fadd_rn(a, b); }
__device__ __forceinline__ float fs(float a, float b) { return __fsub_rn(a, b); }

// ---------------- transpose: (B,Cin,H,W) -> (B,H,W,Cin), 4 images ----------------
__global__ __launch_bounds__(256) void transpose_kernel(
    const float* __restrict__ I, const float* __restrict__ IX,
    const float* __restrict__ IY, const float* __restrict__ IT,
    float* __restrict__ out)
{
    __shared__ float tile[CIN_ * 97];   // [c][y], pad 97 vs bank conflicts
    const int x = blockIdx.x;           // 0..95 (H row)
    const int b = blockIdx.y;           // 0..7
    const int a = blockIdx.z;           // 0..3 image select
    const float* src = (a == 0) ? I : (a == 1) ? IX : (a == 2) ? IY : IT;
    const float* sp = src + (size_t)b * IMG_ + (size_t)x * W_;

    for (int i = threadIdx.x; i < CIN_ * W_; i += 256) {
        int c = i / W_, y = i - c * W_;
        tile[c * 97 + y] = sp[(size_t)c * HW_ + y];
    }
    __syncthreads();
    float* op = out + (size_t)a * (B_ * (size_t)HW_ * CIN_)
                    + (size_t)b * ((size_t)HW_ * CIN_)
                    + (size_t)x * (W_ * CIN_);
    for (int i = threadIdx.x; i < CIN_ * W_; i += 256) {
        int y = i >> 7, c = i & 127;    // i = y*128 + c  -> coalesced writes
        op[i] = tile[c * 97 + y];
    }
}

// ---------------- gather helper: 4 consecutive channels at (xi, yi) ----------------
template <bool NHWC>
__device__ __forceinline__ float4 ld4f(const float* __restrict__ p, int xi, int yi, int c0)
{
    if (NHWC) {
        return *(const float4*)(p + ((size_t)(xi * W_ + yi) * CIN_ + c0));
    } else {
        const float* q = p + (size_t)c0 * HW_ + xi * W_ + yi;
        float4 v;
        v.x = q[0]; v.y = q[HW_]; v.z = q[2 * HW_]; v.w = q[3 * HW_];
        return v;
    }
}

// ---------------- fused per-row megakernel, numpy-f32-faithful ----------------
template <bool NHWC>
__global__ __launch_bounds__(256) void fused_kernel(
    const float* __restrict__ x, const float* __restrict__ r,
    const float* __restrict__ Wr, const float* __restrict__ br,
    const float* __restrict__ Wm, const float* __restrict__ bm,
    const float* __restrict__ Ws, const float* __restrict__ bs,
    const float* __restrict__ lng, const float* __restrict__ lnb,
    const float* __restrict__ gI, const float* __restrict__ gIX,
    const float* __restrict__ gIY, const float* __restrict__ gIT,
    float* __restrict__ out)
{
    const int row = blockIdx.x;        // 0..16383
    const int b   = row >> 11;
    const int tid = threadIdx.x;

    __shared__ __align__(16) float xs[C_];
    __shared__ float mpart[4][64];
    __shared__ float mlog[64];
    __shared__ float ratv[7];
    __shared__ float mask_s[64];       // [s*8+g]
    __shared__ float rects[8][4];      // x1,y1,x2,y2 (unit coords, f32 == np bits)
    __shared__ __align__(16) float S_s[8][CIN_];
    __shared__ __align__(16) float SM_s[8][CIN_];
    __shared__ __align__(16) float yv[C_];
    __shared__ float red[8];
    __shared__ float stats[2];

    // ---- stage 1: load x row into LDS ----
    if (tid < 128) ((float4*)xs)[tid] = ((const float4*)(x + (size_t)row * C_))[tid];
    __syncthreads();

    // ---- stage 2a: mask logit partials (not ceil-critical; parallel split ok) ----
    {
        const int o = tid & 63, q = tid >> 6;
        const float* wp = Wm + (size_t)(q * 128) * 64 + o;
        float acc = 0.f;
        #pragma unroll 8
        for (int i = 0; i < 128; ++i) acc = fmaf(xs[q * 128 + i], wp[(size_t)i * 64], acc);
        mpart[q][o] = acc;
    }
    // ---- stage 2b: ratio logits — OpenBLAS sgemm emulation: kc=384 panels,
    //      each a sequential f32 FMA chain; panels combined with one add; then
    //      bias; sigmoid via f64 (scipy-expit-style single rounding) ----
    if (tid >= 64 && tid < 71) {
        const int o = tid - 64;
        const float* wp = Wr + o;
        float p1 = 0.f, p2 = 0.f;
        for (int k = 0; k < 384; ++k)   p1 = fmaf(xs[k], wp[(size_t)k * 7], p1);
        for (int k = 384; k < 512; ++k) p2 = fmaf(xs[k], wp[(size_t)k * 7], p2);
        const float z = fa(fa(p1, p2), br[o]);
        ratv[o] = (float)(1.0 / (1.0 + exp(-(double)z)));   // expit: f64, one rounding
    }
    __syncthreads();

    if (tid < 64)
        mlog[tid] = fa(fa(fa(fa(mpart[0][tid], mpart[1][tid]), mpart[2][tid]), mpart[3][tid]), bm[tid]);
    __syncthreads();

    // ---- stage 4a: softmax over rects per group (smooth; f32) ----
    if (tid < 8) {
        const int g = tid;
        float mx = -1e30f;
        #pragma unroll
        for (int s = 0; s < 8; ++s) mx = fmaxf(mx, mlog[s * 8 + g]);
        float e[8], sum = 0.f;
        #pragma unroll
        for (int s = 0; s < 8; ++s) { e[s] = expf(mlog[s * 8 + g] - mx); sum += e[s]; }
        const float inv = 1.0f / sum;
        #pragma unroll
        for (int s = 0; s < 8; ++s) mask_s[s * 8 + g] = e[s] * inv;
    }
    // ---- stage 4b: rect split tree, numpy-exact f32 ops ----
    if (tid == 64) {
        float rx1[8], ry1[8], rx2[8], ry2[8];
        const float* rp = r + (size_t)row * 4;
        rx1[0] = rp[0]; ry1[0] = rp[1]; rx2[0] = rp[2]; ry2[0] = rp[3];
        float* lr0 = out + OUT_L0 + (size_t)row * 8;
        float* lr1 = out + OUT_L1 + (size_t)row * 16;
        float* lr2 = out + OUT_L2 + (size_t)row * 32;
        // mid = p_lo*(1-rat) + p_hi*rat  — mul, mul, add (no FMA), like numpy
        {
            const float t = ratv[0];
            const float m = fa(fm(rx1[0], fs(1.0f, t)), fm(rx2[0], t));
            rx1[1] = m; ry1[1] = ry1[0]; rx2[1] = rx2[0]; ry2[1] = ry2[0];
            rx2[0] = m;
        }
        for (int s = 0; s < 2; ++s) {
            lr0[s*4+0] = rx1[s]; lr0[s*4+1] = ry1[s];
            lr0[s*4+2] = rx2[s]; lr0[s*4+3] = ry2[s];
        }
        for (int j = 0; j < 2; ++j) {
            const float t = ratv[1 + j];
            const float m = fa(fm(ry1[j], fs(1.0f, t)), fm(ry2[j], t));
            rx1[2+j] = rx1[j]; ry1[2+j] = m; rx2[2+j] = rx2[j]; ry2[2+j] = ry2[j];
            ry2[j] = m;
        }
        for (int s = 0; s < 4; ++s) {
            lr1[s*4+0] = rx1[s]; lr1[s*4+1] = ry1[s];
            lr1[s*4+2] = rx2[s]; lr1[s*4+3] = ry2[s];
        }
        for (int j = 0; j < 4; ++j) {
            const float t = ratv[3 + j];
            const float m = fa(fm(rx1[j], fs(1.0f, t)), fm(rx2[j], t));
            rx1[4+j] = m; ry1[4+j] = ry1[j]; rx2[4+j] = rx2[j]; ry2[4+j] = ry2[j];
            rx2[j] = m;
        }
        for (int s = 0; s < 8; ++s) {
            lr2[s*4+0] = rx1[s]; lr2[s*4+1] = ry1[s];
            lr2[s*4+2] = rx2[s]; lr2[s*4+3] = ry2[s];
            rects[s][0] = rx1[s]; rects[s][1] = ry1[s];
            rects[s][2] = rx2[s]; rects[s][3] = ry2[s];
        }
    }
    __syncthreads();

    // ---- stage 5: sampling — numpy-exact f32 order ----
    {
        const int s  = tid >> 5;
        const int c0 = (tid & 31) << 2;
        const float X1 = fm(rects[s][0], 95.0f), Y1 = fm(rects[s][1], 95.0f);
        const float X2 = fm(rects[s][2], 95.0f), Y2 = fm(rects[s][3], 95.0f);
        const float area = fa(fabsf(fm(fs(X1, X2), fs(Y1, Y2))), 1e-9f);

        const size_t bb = (size_t)b * IMG_;
        const float* pI  = gI  + bb;
        const float* pIX = gIX + bb;
        const float* pIY = gIY + bb;
        const float* pIT = gIT + bb;

        const float cx[4] = { X2, X1, X2, X1 };   // tl(x2,y2), tl(x1,y2), tl(x2,y1), tl(x1,y1)
        const float cy[4] = { Y2, Y2, Y1, Y1 };
        float4 tlv[4];
        #pragma unroll
        for (int k = 0; k < 4; ++k) {
            const float xx = cx[k], yy = cy[k];
            const float xcf = ceilf(xx), ycf = ceilf(yy);
            const int X = (int)xcf, Y = (int)ycf;
            const int Xm = max(X - 1, 0), Ym = max(Y - 1, 0);
            const float dx = fs(xcf, xx), dy = fs(ycf, yy);
            const float wx1 = fm(0.5f, fm(dx, dx)), wx2 = fs(dx, wx1);
            const float wy1 = fm(0.5f, fm(dy, dy)), wy2 = fs(dy, wy1);

            const float4 it_xy  = ld4f<NHWC>(pIT, X,  Y,  c0);
            const float4 ix_xym = ld4f<NHWC>(pIX, X,  Ym, c0);
            const float4 ix_xy  = ld4f<NHWC>(pIX, X,  Y,  c0);
            const float4 iy_xmy = ld4f<NHWC>(pIY, Xm, Y,  c0);
            const float4 iy_xy  = ld4f<NHWC>(pIY, X,  Y,  c0);
            const float4 i_xym  = ld4f<NHWC>(pI,  X,  Ym, c0);
            const float4 i_0ym  = ld4f<NHWC>(pI,  0,  Ym, c0);
            const float4 i_xy   = ld4f<NHWC>(pI,  X,  Y,  c0);
            const float4 i_0y   = ld4f<NHWC>(pI,  0,  Y,  c0);
            const float4 i_xmy  = ld4f<NHWC>(pI,  Xm, Y,  c0);
            const float4 i_xm0  = ld4f<NHWC>(pI,  Xm, 0,  c0);
            const float4 i_x0   = ld4f<NHWC>(pI,  X,  0,  c0);
            const float4 i_xmym = ld4f<NHWC>(pI,  Xm, Ym, c0);

            #define TLF(f) { \
                const float t1 = fs(fs(ix_xym.f, fm(0.5f, i_xym.f)), fm(0.5f, i_0ym.f)); \
                const float t2 = fs(fs(ix_xy.f,  fm(0.5f, i_xy.f)),  fm(0.5f, i_0y.f)); \
                const float e1 = fa(fm(wy1, t1), fm(wy2, t2)); \
                const float u1 = fs(fs(iy_xmy.f, fm(0.5f, i_xmy.f)), fm(0.5f, i_xm0.f)); \
                const float u2 = fs(fs(iy_xy.f,  fm(0.5f, i_xy.f)),  fm(0.5f, i_x0.f)); \
                const float e2 = fa(fm(wx1, u1), fm(wx2, u2)); \
                const float cc = fa(fa(fa(fm(fm(wx1, wy1), i_xmym.f), \
                                           fm(fm(wx2, wy1), i_xym.f)), \
                                           fm(fm(wx1, wy2), i_xmy.f)), \
                                           fm(fm(wx2, wy2), i_xy.f)); \
                tlv[k].f = fa(fs(fs(it_xy.f, e1), e2), cc); }
            TLF(x) TLF(y) TLF(z) TLF(w)
            #undef TLF
        }
        #define SCOMB(f, idx) { \
            const float sc = fa(fs(fs(tlv[0].f, tlv[1].f), tlv[2].f), tlv[3].f); \
            S_s[s][c0 + idx] = sc / area; }
        SCOMB(x, 0) SCOMB(y, 1) SCOMB(z, 2) SCOMB(w, 3)
        #undef SCOMB
    }
    __syncthreads();

    // ---- stage 6: fold mask into S (b_samp==0 makes this exact) ----
    {
        const int c = tid & 127;
        #pragma unroll
        for (int p = 0; p < 4; ++p) {
            const int g = (tid >> 7) + p * 2;
            float acc = 0.f;
            #pragma unroll
            for (int s = 0; s < 8; ++s) acc = fmaf(mask_s[s * 8 + g], S_s[s][c], acc);
            SM_s[g][c] = acc;
        }
    }
    __syncthreads();

    // ---- stage 7: output matmul: y[o] = bs[o] + sum_c SM[o>>6][c]*Ws[c][o] ----
    {
        float a0 = bs[tid], a1 = bs[tid + 256];
        const int g0 = tid >> 6;
        const int g1 = g0 + 4;
        const float* w0 = Ws + tid;
        #pragma unroll 4
        for (int c = 0; c < 128; ++c) {
            a0 = fmaf(SM_s[g0][c], w0[(size_t)c * 512],       a0);
            a1 = fmaf(SM_s[g1][c], w0[(size_t)c * 512 + 256], a1);
        }
        yv[tid] = a0; yv[tid + 256] = a1;
    }
    __syncthreads();

    // ---- stage 8: LayerNorm + residual ----
    {
        const float v0 = yv[tid], v1 = yv[tid + 256];
        float s1 = v0 + v1, s2 = fmaf(v0, v0, v1 * v1);
        #pragma unroll
        for (int off = 32; off > 0; off >>= 1) {
            s1 += __shfl_down(s1, off);
            s2 += __shfl_down(s2, off);
        }
        if ((tid & 63) == 0) { red[(tid >> 6) * 2] = s1; red[(tid >> 6) * 2 + 1] = s2; }
        __syncthreads();
        if (tid == 0) {
            const float t1 = red[0] + red[2] + red[4] + red[6];
            const float t2 = red[1] + red[3] + red[5] + red[7];
            const float mu = t1 * (1.0f / 512.0f);
            const float var = t2 * (1.0f / 512.0f) - mu * mu;
            stats[0] = mu; stats[1] = rsqrtf(var + 1e-5f);
        }
        __syncthreads();
        const float mu = stats[0], rstd = stats[1];
        float* op = out + (size_t)row * C_;
        op[tid]       = (v0 - mu) * rstd * lng[tid]       + lnb[tid]       + xs[tid];
        op[tid + 256] = (v1 - mu) * rstd * lng[tid + 256] + lnb[tid + 256] + xs[tid + 256];
    }
}

extern "C" void kernel_launch(void* const* d_in, const int* in_sizes, int n_in,
                              void* d_out, int out_size, void* d_ws, size_t ws_size,
                              hipStream_t stream)
{
    const float* x   = (const float*)d_in[0];
    const float* r   = (const float*)d_in[1];
    const float* I   = (const float*)d_in[2];
    const float* IX  = (const float*)d_in[3];
    const float* IY  = (const float*)d_in[4];
    const float* IT  = (const float*)d_in[5];
    const float* Wr  = (const float*)d_in[6];
    const float* br  = (const float*)d_in[7];
    const float* Wm  = (const float*)d_in[8];
    const float* bm  = (const float*)d_in[9];
    const float* Ws  = (const float*)d_in[10];
    const float* bs  = (const float*)d_in[11];
    const float* lng = (const float*)d_in[12];
    const float* lnb = (const float*)d_in[13];
    float* out = (float*)d_out;

    const size_t img_elems = (size_t)B_ * HW_ * CIN_;        // 9437184
    const size_t need = 4 * img_elems * sizeof(float);       // ~151 MB

    if (ws_size >= need) {
        float* T = (float*)d_ws;
        dim3 tg(H_, B_, 4);
        transpose_kernel<<<tg, 256, 0, stream>>>(I, IX, IY, IT, T);
        fused_kernel<true><<<B_ * N_, 256, 0, stream>>>(
            x, r, Wr, br, Wm, bm, Ws, bs, lng, lnb,
            T, T + img_elems, T + 2 * img_elems, T + 3 * img_elems, out);
    } else {
        fused_kernel<false><<<B_ * N_, 256, 0, stream>>>(
            x, r, Wr, br, Wm, bm, Ws, bs, lng, lnb,
            I, IX, IY, IT, out);
    }
}